// Round 1
// baseline (1688.443 us; speedup 1.0000x reference)
//
#include <hip/hip_runtime.h>
#include <hip/hip_bf16.h>

#define NTOK 4096   // B*T
#define HDIM 1024
#define IDIM 2048
#define NEXP 8

// ---------------- routing: 1 block (256 thr) per token ----------------
__global__ __launch_bounds__(256) void routing_kernel(
    const float* __restrict__ x, const float* __restrict__ qw,
    const float* __restrict__ kp, const float* __restrict__ vp,
    float* __restrict__ rw_out, int* __restrict__ counts,
    int* __restrict__ list, int2* __restrict__ tope, float2* __restrict__ topw)
{
    int t = blockIdx.x;
    int tid = threadIdx.x;
    __shared__ float ssq_s[4];
    __shared__ float red[NEXP * 4];

    const float* xr = x + (size_t)t * HDIM;
    float4 xv = ((const float4*)xr)[tid];          // h = tid*4 .. +3
    float ss = xv.x*xv.x + xv.y*xv.y + xv.z*xv.z + xv.w*xv.w;
    #pragma unroll
    for (int off = 32; off; off >>= 1) ss += __shfl_down(ss, off);
    int wave = tid >> 6, lane = tid & 63;
    if (lane == 0) ssq_s[wave] = ss;
    __syncthreads();
    float ssq = ssq_s[0] + ssq_s[1] + ssq_s[2] + ssq_s[3];
    float rms = rsqrtf(ssq * (1.0f / HDIM) + 1e-6f);

    float4 qv = ((const float4*)qw)[tid];
    float q0 = xv.x * rms * qv.x, q1 = xv.y * rms * qv.y;
    float q2 = xv.z * rms * qv.z, q3 = xv.w * rms * qv.w;

    float part[NEXP];
    #pragma unroll
    for (int p = 0; p < NEXP; p++) {
        float4 kv = ((const float4*)(kp + (size_t)p * HDIM))[tid];
        part[p] = q0*kv.x + q1*kv.y + q2*kv.z + q3*kv.w;
    }
    #pragma unroll
    for (int p = 0; p < NEXP; p++) {
        float v = part[p];
        #pragma unroll
        for (int off = 32; off; off >>= 1) v += __shfl_down(v, off);
        if (lane == 0) red[p * 4 + wave] = v;
    }
    __syncthreads();
    if (tid == 0) {
        float d[NEXP];
        #pragma unroll
        for (int p = 0; p < NEXP; p++)
            d[p] = (red[p*4] + red[p*4+1] + red[p*4+2] + red[p*4+3]) * (1.0f / 32.0f);
        // softmax over proto scores
        float m = d[0];
        #pragma unroll
        for (int p = 1; p < NEXP; p++) m = fmaxf(m, d[p]);
        float a[NEXP]; float s = 0.f;
        #pragma unroll
        for (int p = 0; p < NEXP; p++) { a[p] = expf(d[p] - m); s += a[p]; }
        float inv = 1.0f / s;
        #pragma unroll
        for (int p = 0; p < NEXP; p++) a[p] *= inv;
        // logits = attn @ v_proto (ROUTING_GAIN = 1)
        float lg[NEXP];
        #pragma unroll
        for (int q = 0; q < NEXP; q++) {
            float acc = 0.f;
            #pragma unroll
            for (int p = 0; p < NEXP; p++) acc += a[p] * vp[p * NEXP + q];
            lg[q] = acc;
        }
        float m2 = lg[0];
        #pragma unroll
        for (int p = 1; p < NEXP; p++) m2 = fmaxf(m2, lg[p]);
        float r[NEXP]; float s2 = 0.f;
        #pragma unroll
        for (int p = 0; p < NEXP; p++) { r[p] = expf(lg[p] - m2); s2 += r[p]; }
        float inv2 = 1.0f / s2;
        #pragma unroll
        for (int p = 0; p < NEXP; p++) r[p] *= inv2;
        // top-2 (earliest index wins ties, matches lax.top_k)
        int e0 = -1, e1 = -1; float w0 = -1.f, w1 = -1.f;
        #pragma unroll
        for (int p = 0; p < NEXP; p++) {
            if (r[p] > w0) { w1 = w0; e1 = e0; w0 = r[p]; e0 = p; }
            else if (r[p] > w1) { w1 = r[p]; e1 = p; }
        }
        float invn = 1.0f / (w0 + w1 + 1e-9f);
        float w0n = w0 * invn, w1n = w1 * invn;
        #pragma unroll
        for (int p = 0; p < NEXP; p++)
            rw_out[(size_t)t * NEXP + p] = (p == e0) ? w0n : ((p == e1) ? w1n : 0.f);
        tope[t] = make_int2(e0, e1);
        topw[t] = make_float2(w0n, w1n);
        int p0 = atomicAdd(&counts[e0], 1); list[e0 * NTOK + p0] = t * 2;
        int p1 = atomicAdd(&counts[e1], 1); list[e1 * NTOK + p1] = t * 2 + 1;
    }
}

// ------------- grouped GEMM: gate|up  (A = gathered x rows) -------------
// tile 128x128, TK=16, 256 threads, 8x8 micro-tile
#define TM 128
#define TN 128
#define TK 16
#define LDAS (TM + 8)
#define LDBS (TN + 8)

__global__ __launch_bounds__(256) void gemm_gu(
    const float* __restrict__ x, const float* __restrict__ gate,
    const float* __restrict__ up, const int* __restrict__ counts,
    const int* __restrict__ list, float* __restrict__ bg, float* __restrict__ bu)
{
    int e = blockIdx.z;
    int M = counts[e];
    int row0 = blockIdx.y * TM;
    if (row0 >= M) return;
    int col0 = blockIdx.x * TN;          // 0..4095 (gate cols then up cols)
    const float* Bp = (col0 < IDIM) ? (gate + (size_t)e * HDIM * IDIM + col0)
                                    : (up   + (size_t)e * HDIM * IDIM + (col0 - IDIM));
    float* outbuf = (col0 < IDIM) ? bg : bu;
    int ocol = (col0 < IDIM) ? col0 : col0 - IDIM;

    __shared__ int rows[TM];
    __shared__ float As[TK][LDAS];   // K-major
    __shared__ float Bs[TK][LDBS];

    int tid = threadIdx.x;
    if (tid < TM) {
        int r = row0 + tid;
        rows[tid] = (r < M) ? list[e * NTOK + r] : -1;
    }
    __syncthreads();

    int tx = tid & 15, ty = tid >> 4;
    int ra = tid >> 2, ka = (tid & 3) * 4;      // A stage: rows ra, ra+64
    int kb = tid >> 4, cb = (tid & 15) * 8;     // B stage

    float acc[8][8] = {};

    for (int k0 = 0; k0 < HDIM; k0 += TK) {
        int ent0 = rows[ra];
        int ent1 = rows[ra + 64];
        float4 av0 = make_float4(0,0,0,0), av1 = make_float4(0,0,0,0);
        if (ent0 >= 0) av0 = *(const float4*)(x + (size_t)(ent0 >> 1) * HDIM + k0 + ka);
        if (ent1 >= 0) av1 = *(const float4*)(x + (size_t)(ent1 >> 1) * HDIM + k0 + ka);
        float4 bv0 = *(const float4*)(Bp + (size_t)(k0 + kb) * IDIM + cb);
        float4 bv1 = *(const float4*)(Bp + (size_t)(k0 + kb) * IDIM + cb + 4);
        __syncthreads();
        As[ka+0][ra] = av0.x; As[ka+1][ra] = av0.y; As[ka+2][ra] = av0.z; As[ka+3][ra] = av0.w;
        As[ka+0][ra+64] = av1.x; As[ka+1][ra+64] = av1.y; As[ka+2][ra+64] = av1.z; As[ka+3][ra+64] = av1.w;
        *(float4*)&Bs[kb][cb] = bv0;
        *(float4*)&Bs[kb][cb + 4] = bv1;
        __syncthreads();
        #pragma unroll
        for (int k = 0; k < TK; k++) {
            float4 a0 = *(const float4*)&As[k][ty * 8];
            float4 a1 = *(const float4*)&As[k][ty * 8 + 4];
            float4 b0 = *(const float4*)&Bs[k][tx * 8];
            float4 b1 = *(const float4*)&Bs[k][tx * 8 + 4];
            float av[8] = {a0.x,a0.y,a0.z,a0.w,a1.x,a1.y,a1.z,a1.w};
            float bvv[8] = {b0.x,b0.y,b0.z,b0.w,b1.x,b1.y,b1.z,b1.w};
            #pragma unroll
            for (int j = 0; j < 8; j++)
                #pragma unroll
                for (int l = 0; l < 8; l++)
                    acc[j][l] = fmaf(av[j], bvv[l], acc[j][l]);
        }
    }
    #pragma unroll
    for (int j = 0; j < 8; j++) {
        int ent = rows[ty * 8 + j];
        if (ent >= 0) {
            float* op = outbuf + (size_t)ent * IDIM + ocol + tx * 8;
            float4 s0 = make_float4(acc[j][0], acc[j][1], acc[j][2], acc[j][3]);
            float4 s1 = make_float4(acc[j][4], acc[j][5], acc[j][6], acc[j][7]);
            *(float4*)op = s0;
            *(float4*)(op + 4) = s1;
        }
    }
}

// ------------- elementwise: mix pairs, silu, produce inter -------------
__global__ __launch_bounds__(256) void silu_mix(
    const float* __restrict__ bg, const float* __restrict__ bu,
    const float2* __restrict__ topw, float* __restrict__ inter)
{
    int idx = blockIdx.x * 256 + threadIdx.x;          // over NTOK*IDIM/4
    int t = idx >> 9;                                  // IDIM/4 = 512
    int i4 = (idx & 511) * 4;
    float2 w = topw[t];
    float4 g0 = *(const float4*)(bg + (size_t)(2*t)   * IDIM + i4);
    float4 g1 = *(const float4*)(bg + (size_t)(2*t+1) * IDIM + i4);
    float4 u0 = *(const float4*)(bu + (size_t)(2*t)   * IDIM + i4);
    float4 u1 = *(const float4*)(bu + (size_t)(2*t+1) * IDIM + i4);
    float4 r;
    float g, u;
    g = w.x*g0.x + w.y*g1.x; u = w.x*u0.x + w.y*u1.x; r.x = g / (1.f + expf(-g)) * u;
    g = w.x*g0.y + w.y*g1.y; u = w.x*u0.y + w.y*u1.y; r.y = g / (1.f + expf(-g)) * u;
    g = w.x*g0.z + w.y*g1.z; u = w.x*u0.z + w.y*u1.z; r.z = g / (1.f + expf(-g)) * u;
    g = w.x*g0.w + w.y*g1.w; u = w.x*u0.w + w.y*u1.w; r.w = g / (1.f + expf(-g)) * u;
    *(float4*)(inter + (size_t)t * IDIM + i4) = r;
}

// ------------- grouped GEMM: down (A = gathered inter rows) -------------
__global__ __launch_bounds__(256) void gemm_down(
    const float* __restrict__ inter, const float* __restrict__ down,
    const int* __restrict__ counts, const int* __restrict__ list,
    float* __restrict__ pout)
{
    int e = blockIdx.z;
    int M = counts[e];
    int row0 = blockIdx.y * TM;
    if (row0 >= M) return;
    int col0 = blockIdx.x * TN;          // 0..1023
    const float* Bp = down + (size_t)e * IDIM * HDIM + col0;

    __shared__ int rows[TM];
    __shared__ float As[TK][LDAS];
    __shared__ float Bs[TK][LDBS];

    int tid = threadIdx.x;
    if (tid < TM) {
        int r = row0 + tid;
        rows[tid] = (r < M) ? list[e * NTOK + r] : -1;
    }
    __syncthreads();

    int tx = tid & 15, ty = tid >> 4;
    int ra = tid >> 2, ka = (tid & 3) * 4;
    int kb = tid >> 4, cb = (tid & 15) * 8;

    float acc[8][8] = {};

    for (int k0 = 0; k0 < IDIM; k0 += TK) {
        int ent0 = rows[ra];
        int ent1 = rows[ra + 64];
        float4 av0 = make_float4(0,0,0,0), av1 = make_float4(0,0,0,0);
        if (ent0 >= 0) av0 = *(const float4*)(inter + (size_t)(ent0 >> 1) * IDIM + k0 + ka);
        if (ent1 >= 0) av1 = *(const float4*)(inter + (size_t)(ent1 >> 1) * IDIM + k0 + ka);
        float4 bv0 = *(const float4*)(Bp + (size_t)(k0 + kb) * HDIM + cb);
        float4 bv1 = *(const float4*)(Bp + (size_t)(k0 + kb) * HDIM + cb + 4);
        __syncthreads();
        As[ka+0][ra] = av0.x; As[ka+1][ra] = av0.y; As[ka+2][ra] = av0.z; As[ka+3][ra] = av0.w;
        As[ka+0][ra+64] = av1.x; As[ka+1][ra+64] = av1.y; As[ka+2][ra+64] = av1.z; As[ka+3][ra+64] = av1.w;
        *(float4*)&Bs[kb][cb] = bv0;
        *(float4*)&Bs[kb][cb + 4] = bv1;
        __syncthreads();
        #pragma unroll
        for (int k = 0; k < TK; k++) {
            float4 a0 = *(const float4*)&As[k][ty * 8];
            float4 a1 = *(const float4*)&As[k][ty * 8 + 4];
            float4 b0 = *(const float4*)&Bs[k][tx * 8];
            float4 b1 = *(const float4*)&Bs[k][tx * 8 + 4];
            float av[8] = {a0.x,a0.y,a0.z,a0.w,a1.x,a1.y,a1.z,a1.w};
            float bvv[8] = {b0.x,b0.y,b0.z,b0.w,b1.x,b1.y,b1.z,b1.w};
            #pragma unroll
            for (int j = 0; j < 8; j++)
                #pragma unroll
                for (int l = 0; l < 8; l++)
                    acc[j][l] = fmaf(av[j], bvv[l], acc[j][l]);
        }
    }
    #pragma unroll
    for (int j = 0; j < 8; j++) {
        int ent = rows[ty * 8 + j];
        if (ent >= 0) {
            float* op = pout + (size_t)ent * HDIM + col0 + tx * 8;
            *(float4*)op     = make_float4(acc[j][0], acc[j][1], acc[j][2], acc[j][3]);
            *(float4*)(op+4) = make_float4(acc[j][4], acc[j][5], acc[j][6], acc[j][7]);
        }
    }
}

// ------------- final: weighted pair reduce into output -------------
__global__ __launch_bounds__(256) void out_mix(
    const float* __restrict__ pout, const float2* __restrict__ topw,
    float* __restrict__ out)
{
    int idx = blockIdx.x * 256 + threadIdx.x;          // over NTOK*HDIM/4
    int t = idx >> 8;                                  // HDIM/4 = 256
    int h4 = (idx & 255) * 4;
    float2 w = topw[t];
    float4 a = *(const float4*)(pout + (size_t)(2*t)   * HDIM + h4);
    float4 b = *(const float4*)(pout + (size_t)(2*t+1) * HDIM + h4);
    float4 r;
    r.x = w.x*a.x + w.y*b.x;
    r.y = w.x*a.y + w.y*b.y;
    r.z = w.x*a.z + w.y*b.z;
    r.w = w.x*a.w + w.y*b.w;
    *(float4*)(out + (size_t)t * HDIM + h4) = r;
}

extern "C" void kernel_launch(void* const* d_in, const int* in_sizes, int n_in,
                              void* d_out, int out_size, void* d_ws, size_t ws_size,
                              hipStream_t stream) {
    const float* x    = (const float*)d_in[0];
    const float* qw   = (const float*)d_in[1];
    const float* kp   = (const float*)d_in[2];
    const float* vp   = (const float*)d_in[3];
    const float* gate = (const float*)d_in[4];
    const float* up   = (const float*)d_in[5];
    const float* down = (const float*)d_in[6];
    float* out = (float*)d_out;
    float* rw_out = out + (size_t)NTOK * HDIM;

    char* ws = (char*)d_ws;
    int*    counts = (int*)(ws);
    int2*   tope   = (int2*)(ws + 4096);
    float2* topw   = (float2*)(ws + 36864);
    int*    list   = (int*)(ws + 69632);
    float*  bg     = (float*)(ws + (1u << 20));
    float*  bu     = bg + (size_t)2 * NTOK * IDIM;       // 8192 x 2048
    float*  inter  = bu + (size_t)2 * NTOK * IDIM;
    float*  pout   = inter + (size_t)NTOK * IDIM;

    hipMemsetAsync(counts, 0, NEXP * sizeof(int), stream);
    routing_kernel<<<NTOK, 256, 0, stream>>>(x, qw, kp, vp, rw_out, counts, list, tope, topw);

    dim3 g2(2 * IDIM / TN, NTOK / TM, NEXP);   // (32, 32, 8)
    gemm_gu<<<g2, 256, 0, stream>>>(x, gate, up, counts, list, bg, bu);

    silu_mix<<<(NTOK * IDIM / 4) / 256, 256, 0, stream>>>(bg, bu, topw, inter);

    dim3 g4(HDIM / TN, NTOK / TM, NEXP);       // (8, 32, 8)
    gemm_down<<<g4, 256, 0, stream>>>(inter, down, counts, list, pout);

    out_mix<<<(NTOK * HDIM / 4) / 256, 256, 0, stream>>>(pout, topw, out);
}

// Round 2
// 407.704 us; speedup vs baseline: 4.1413x; 4.1413x over previous
//
#include <hip/hip_runtime.h>
#include <hip/hip_bf16.h>

#define NTOK 4096   // B*T
#define HDIM 1024
#define IDIM 2048
#define NEXP 8

typedef __attribute__((ext_vector_type(8))) short short8;
typedef __attribute__((ext_vector_type(4))) float f32x4;
typedef unsigned short ushort_t;

__device__ inline ushort_t f2bf(float f) {
    union { float f; unsigned u; } v; v.f = f;
    unsigned r = v.u + 0x7FFFu + ((v.u >> 16) & 1u);
    return (ushort_t)(r >> 16);
}
__device__ inline float bf2f(ushort_t h) {
    union { unsigned u; float f; } v; v.u = ((unsigned)h) << 16;
    return v.f;
}

#define GPTR(p) ((const __attribute__((address_space(1))) void*)(p))
#define LPTR(p) ((__attribute__((address_space(3))) void*)(p))

// ---------------- routing: 1 block (256 thr) per token ----------------
__global__ __launch_bounds__(256) void routing_kernel(
    const float* __restrict__ x, const float* __restrict__ qw,
    const float* __restrict__ kp, const float* __restrict__ vp,
    float* __restrict__ rw_out, int* __restrict__ counts,
    int* __restrict__ list, float2* __restrict__ topw)
{
    int t = blockIdx.x;
    int tid = threadIdx.x;
    __shared__ float ssq_s[4];
    __shared__ float red[NEXP * 4];

    const float* xr = x + (size_t)t * HDIM;
    float4 xv = ((const float4*)xr)[tid];
    float ss = xv.x*xv.x + xv.y*xv.y + xv.z*xv.z + xv.w*xv.w;
    #pragma unroll
    for (int off = 32; off; off >>= 1) ss += __shfl_down(ss, off);
    int wave = tid >> 6, lane = tid & 63;
    if (lane == 0) ssq_s[wave] = ss;
    __syncthreads();
    float ssq = ssq_s[0] + ssq_s[1] + ssq_s[2] + ssq_s[3];
    float rms = rsqrtf(ssq * (1.0f / HDIM) + 1e-6f);

    float4 qv = ((const float4*)qw)[tid];
    float q0 = xv.x * rms * qv.x, q1 = xv.y * rms * qv.y;
    float q2 = xv.z * rms * qv.z, q3 = xv.w * rms * qv.w;

    float part[NEXP];
    #pragma unroll
    for (int p = 0; p < NEXP; p++) {
        float4 kv = ((const float4*)(kp + (size_t)p * HDIM))[tid];
        part[p] = q0*kv.x + q1*kv.y + q2*kv.z + q3*kv.w;
    }
    #pragma unroll
    for (int p = 0; p < NEXP; p++) {
        float v = part[p];
        #pragma unroll
        for (int off = 32; off; off >>= 1) v += __shfl_down(v, off);
        if (lane == 0) red[p * 4 + wave] = v;
    }
    __syncthreads();
    if (tid == 0) {
        float d[NEXP];
        #pragma unroll
        for (int p = 0; p < NEXP; p++)
            d[p] = (red[p*4] + red[p*4+1] + red[p*4+2] + red[p*4+3]) * (1.0f / 32.0f);
        float m = d[0];
        #pragma unroll
        for (int p = 1; p < NEXP; p++) m = fmaxf(m, d[p]);
        float a[NEXP]; float s = 0.f;
        #pragma unroll
        for (int p = 0; p < NEXP; p++) { a[p] = expf(d[p] - m); s += a[p]; }
        float inv = 1.0f / s;
        #pragma unroll
        for (int p = 0; p < NEXP; p++) a[p] *= inv;
        float lg[NEXP];
        #pragma unroll
        for (int q = 0; q < NEXP; q++) {
            float acc = 0.f;
            #pragma unroll
            for (int p = 0; p < NEXP; p++) acc += a[p] * vp[p * NEXP + q];
            lg[q] = acc;
        }
        float m2 = lg[0];
        #pragma unroll
        for (int p = 1; p < NEXP; p++) m2 = fmaxf(m2, lg[p]);
        float r[NEXP]; float s2 = 0.f;
        #pragma unroll
        for (int p = 0; p < NEXP; p++) { r[p] = expf(lg[p] - m2); s2 += r[p]; }
        float inv2 = 1.0f / s2;
        #pragma unroll
        for (int p = 0; p < NEXP; p++) r[p] *= inv2;
        int e0 = -1, e1 = -1; float w0 = -1.f, w1 = -1.f;
        #pragma unroll
        for (int p = 0; p < NEXP; p++) {
            if (r[p] > w0) { w1 = w0; e1 = e0; w0 = r[p]; e0 = p; }
            else if (r[p] > w1) { w1 = r[p]; e1 = p; }
        }
        float invn = 1.0f / (w0 + w1 + 1e-9f);
        float w0n = w0 * invn, w1n = w1 * invn;
        #pragma unroll
        for (int p = 0; p < NEXP; p++)
            rw_out[(size_t)t * NEXP + p] = (p == e0) ? w0n : ((p == e1) ? w1n : 0.f);
        topw[t] = make_float2(w0n, w1n);
        int p0 = atomicAdd(&counts[e0], 1); list[e0 * NTOK + p0] = t * 2;
        int p1 = atomicAdd(&counts[e1], 1); list[e1 * NTOK + p1] = t * 2 + 1;
    }
}

// ------- convert x fp32 -> bf16 (no transpose) -------
__global__ __launch_bounds__(256) void conv_x(const float* __restrict__ in, ushort_t* __restrict__ out) {
    int i = blockIdx.x * 256 + threadIdx.x;   // each handles 8 elems
    float4 a = ((const float4*)in)[i * 2];
    float4 b = ((const float4*)in)[i * 2 + 1];
    short8 o;
    o[0]=f2bf(a.x); o[1]=f2bf(a.y); o[2]=f2bf(a.z); o[3]=f2bf(a.w);
    o[4]=f2bf(b.x); o[5]=f2bf(b.y); o[6]=f2bf(b.z); o[7]=f2bf(b.w);
    ((short8*)out)[i] = o;
}

// ------- convert + transpose weights: fp32 [E][K][N] -> bf16 [E][N][K] -------
// grid (N/64, K/64, E), block 256
__global__ __launch_bounds__(256) void conv_t(const float* __restrict__ in, ushort_t* __restrict__ out,
                                              int K, int N) {
    __shared__ ushort_t ts[64][72];
    int e = blockIdx.z;
    const float* ip = in + (size_t)e * K * N + (size_t)(blockIdx.y * 64) * N + blockIdx.x * 64;
    ushort_t* op = out + (size_t)e * K * N + (size_t)(blockIdx.x * 64) * K + blockIdx.y * 64;
    int tid = threadIdx.x;
    int r0 = tid >> 4;            // 0..15
    int c4 = (tid & 15) * 4;
    #pragma unroll
    for (int i = 0; i < 4; i++) {
        int r = r0 + i * 16;
        float4 v = *(const float4*)(ip + (size_t)r * N + c4);
        ts[c4+0][r] = f2bf(v.x); ts[c4+1][r] = f2bf(v.y);
        ts[c4+2][r] = f2bf(v.z); ts[c4+3][r] = f2bf(v.w);
    }
    __syncthreads();
    int n = tid >> 2;             // 0..63
    int kq = (tid & 3) * 16;
    short8 w0 = *(const short8*)&ts[n][kq];
    short8 w1 = *(const short8*)&ts[n][kq + 8];
    ushort_t* dst = op + (size_t)n * K + kq;
    ((short8*)dst)[0] = w0;
    ((short8*)dst)[1] = w1;
}

// ------- grouped bf16 MFMA GEMM: C[ent][col] = sum_k A[tok][k] * Wt[e][col][k] -------
// tile 128x128, BK=32, 256 threads (4 waves as 2x2 of 64x64), m97-style global_load_lds
template<int K, int OUTBF>
__global__ __launch_bounds__(256) void gemm_bf16(
    const ushort_t* __restrict__ A, const ushort_t* __restrict__ W,
    const int* __restrict__ counts, const int* __restrict__ list,
    void* __restrict__ outp, int odim)
{
    int e = blockIdx.z;
    int M = counts[e];
    int row0 = blockIdx.y * 128;
    if (row0 >= M) return;
    int col0 = blockIdx.x * 128;

    __shared__ ushort_t Abuf[128 * 32];
    __shared__ ushort_t Bbuf[128 * 32];
    __shared__ int rowsS[128];

    int tid = threadIdx.x;
    if (tid < 128) {
        int r = row0 + tid;
        rowsS[tid] = (r < M) ? list[e * NTOK + r] : -1;
    }
    __syncthreads();

    // staging sources: slot s covers LDS row s>>2, k-chunk s&3 (8 bf16 = 16B each)
    int s0 = tid, s1 = tid + 256;
    int er0 = rowsS[s0 >> 2], er1 = rowsS[s1 >> 2];
    const ushort_t* gA0 = A + (size_t)(er0 >= 0 ? (er0 >> 1) : 0) * K + (s0 & 3) * 8;
    const ushort_t* gA1 = A + (size_t)(er1 >= 0 ? (er1 >> 1) : 0) * K + (s1 & 3) * 8;
    const ushort_t* We = W + (size_t)e * odim * K;
    const ushort_t* gB0 = We + (size_t)(col0 + (s0 >> 2)) * K + (s0 & 3) * 8;
    const ushort_t* gB1 = We + (size_t)(col0 + (s1 >> 2)) * K + (s1 & 3) * 8;

    int wid = tid >> 6, lane = tid & 63;
    int wr = wid >> 1, wc = wid & 1;
    int la = lane & 15, lb = lane >> 4;

    // per-wave uniform LDS staging bases (HW adds lane*16B)
    ushort_t* ldsA = Abuf + wid * 64 * 8;
    ushort_t* ldsB = Bbuf + wid * 64 * 8;

    // fragment read offsets (ushort index), k0-independent
    int aoff[4], boff[4];
    #pragma unroll
    for (int m = 0; m < 4; m++) aoff[m] = (wr * 64 + m * 16 + la) * 32 + lb * 8;
    #pragma unroll
    for (int n = 0; n < 4; n++) boff[n] = (wc * 64 + n * 16 + la) * 32 + lb * 8;

    f32x4 acc[4][4];
    #pragma unroll
    for (int m = 0; m < 4; m++)
        #pragma unroll
        for (int n = 0; n < 4; n++) acc[m][n] = (f32x4){0.f, 0.f, 0.f, 0.f};

    for (int k0 = 0; k0 < K; k0 += 32) {
        __builtin_amdgcn_global_load_lds(GPTR(gA0 + k0), LPTR(ldsA),            16, 0, 0);
        __builtin_amdgcn_global_load_lds(GPTR(gA1 + k0), LPTR(ldsA + 256 * 8),  16, 0, 0);
        __builtin_amdgcn_global_load_lds(GPTR(gB0 + k0), LPTR(ldsB),            16, 0, 0);
        __builtin_amdgcn_global_load_lds(GPTR(gB1 + k0), LPTR(ldsB + 256 * 8),  16, 0, 0);
        __syncthreads();
        short8 af[4], bfr[4];
        #pragma unroll
        for (int m = 0; m < 4; m++) af[m] = *(const short8*)&Abuf[aoff[m]];
        #pragma unroll
        for (int n = 0; n < 4; n++) bfr[n] = *(const short8*)&Bbuf[boff[n]];
        #pragma unroll
        for (int m = 0; m < 4; m++)
            #pragma unroll
            for (int n = 0; n < 4; n++)
                acc[m][n] = __builtin_amdgcn_mfma_f32_16x16x32_bf16(af[m], bfr[n], acc[m][n], 0, 0, 0);
        __syncthreads();
    }

    // epilogue: lane holds rows (lane>>4)*4+j, col la within each 16x16 frag
    #pragma unroll
    for (int m = 0; m < 4; m++) {
        #pragma unroll
        for (int j = 0; j < 4; j++) {
            int rl = wr * 64 + m * 16 + lb * 4 + j;
            int ent = rowsS[rl];
            if (ent >= 0) {
                size_t base = (size_t)ent * odim + col0 + wc * 64 + la;
                #pragma unroll
                for (int n = 0; n < 4; n++) {
                    if (OUTBF) ((ushort_t*)outp)[base + n * 16] = f2bf(acc[m][n][j]);
                    else       ((float*)outp)[base + n * 16] = acc[m][n][j];
                }
            }
        }
    }
}

// ------- elementwise: mix pairs (bf16 in), silu, write bf16 inter -------
__global__ __launch_bounds__(256) void silu_mix(
    const ushort_t* __restrict__ bg, const ushort_t* __restrict__ bu,
    const float2* __restrict__ topw, ushort_t* __restrict__ inter)
{
    int idx = blockIdx.x * 256 + threadIdx.x;          // over NTOK*IDIM/8
    int t = idx >> 8;                                  // IDIM/8 = 256
    int i8 = (idx & 255) * 8;
    float2 w = topw[t];
    short8 g0 = *(const short8*)(bg + (size_t)(2*t)   * IDIM + i8);
    short8 g1 = *(const short8*)(bg + (size_t)(2*t+1) * IDIM + i8);
    short8 u0 = *(const short8*)(bu + (size_t)(2*t)   * IDIM + i8);
    short8 u1 = *(const short8*)(bu + (size_t)(2*t+1) * IDIM + i8);
    short8 r;
    #pragma unroll
    for (int j = 0; j < 8; j++) {
        float g = w.x * bf2f((ushort_t)g0[j]) + w.y * bf2f((ushort_t)g1[j]);
        float u = w.x * bf2f((ushort_t)u0[j]) + w.y * bf2f((ushort_t)u1[j]);
        float s = g / (1.f + expf(-g)) * u;
        r[j] = f2bf(s);
    }
    *(short8*)(inter + (size_t)t * IDIM + i8) = r;
}

// ------- final: weighted pair reduce into output -------
__global__ __launch_bounds__(256) void out_mix(
    const float* __restrict__ pout, const float2* __restrict__ topw,
    float* __restrict__ out)
{
    int idx = blockIdx.x * 256 + threadIdx.x;          // over NTOK*HDIM/4
    int t = idx >> 8;                                  // HDIM/4 = 256
    int h4 = (idx & 255) * 4;
    float2 w = topw[t];
    float4 a = *(const float4*)(pout + (size_t)(2*t)   * HDIM + h4);
    float4 b = *(const float4*)(pout + (size_t)(2*t+1) * HDIM + h4);
    float4 r;
    r.x = w.x*a.x + w.y*b.x;
    r.y = w.x*a.y + w.y*b.y;
    r.z = w.x*a.z + w.y*b.z;
    r.w = w.x*a.w + w.y*b.w;
    *(float4*)(out + (size_t)t * HDIM + h4) = r;
}

extern "C" void kernel_launch(void* const* d_in, const int* in_sizes, int n_in,
                              void* d_out, int out_size, void* d_ws, size_t ws_size,
                              hipStream_t stream) {
    const float* x    = (const float*)d_in[0];
    const float* qw   = (const float*)d_in[1];
    const float* kp   = (const float*)d_in[2];
    const float* vp   = (const float*)d_in[3];
    const float* gate = (const float*)d_in[4];
    const float* up   = (const float*)d_in[5];
    const float* down = (const float*)d_in[6];
    float* out = (float*)d_out;
    float* rw_out = out + (size_t)NTOK * HDIM;

    char* ws = (char*)d_ws;
    int*      counts = (int*)ws;                          // 32 B
    float2*   topw   = (float2*)(ws + 1024);              // 32 KB
    int*      list   = (int*)(ws + 64 * 1024);            // 128 KB
    ushort_t* xb     = (ushort_t*)(ws + 256 * 1024);      // 8 MB
    ushort_t* wtg    = xb + (size_t)NTOK * HDIM;          // 32 MB  (bf16 [E][I][H])
    ushort_t* wtu    = wtg + (size_t)NEXP * HDIM * IDIM;  // 32 MB
    ushort_t* wtd    = wtu + (size_t)NEXP * HDIM * IDIM;  // 32 MB  (bf16 [E][H][I])
    ushort_t* bg     = wtd + (size_t)NEXP * HDIM * IDIM;  // 33.5 MB (bf16 [8192][I])
    ushort_t* bu     = bg  + (size_t)2 * NTOK * IDIM;     // 33.5 MB
    ushort_t* interb = bu  + (size_t)2 * NTOK * IDIM;     // 16.8 MB (bf16 [NTOK][I])
    float*    pout   = (float*)bg;                        // alias (bg dead after silu_mix)

    hipMemsetAsync(counts, 0, NEXP * sizeof(int), stream);

    conv_x<<<NTOK * HDIM / 8 / 256, 256, 0, stream>>>(x, xb);
    conv_t<<<dim3(IDIM / 64, HDIM / 64, NEXP), 256, 0, stream>>>(gate, wtg, HDIM, IDIM);
    conv_t<<<dim3(IDIM / 64, HDIM / 64, NEXP), 256, 0, stream>>>(up,   wtu, HDIM, IDIM);
    conv_t<<<dim3(HDIM / 64, IDIM / 64, NEXP), 256, 0, stream>>>(down, wtd, IDIM, HDIM);

    routing_kernel<<<NTOK, 256, 0, stream>>>(x, qw, kp, vp, rw_out, counts, list, topw);

    dim3 ggu(IDIM / 128, NTOK / 128, NEXP);   // (16, 32, 8)
    gemm_bf16<HDIM, 1><<<ggu, 256, 0, stream>>>(xb, wtg, counts, list, bg, IDIM);
    gemm_bf16<HDIM, 1><<<ggu, 256, 0, stream>>>(xb, wtu, counts, list, bu, IDIM);

    silu_mix<<<NTOK * IDIM / 8 / 256, 256, 0, stream>>>(bg, bu, topw, interb);

    dim3 gd(HDIM / 128, NTOK / 128, NEXP);    // (8, 32, 8)
    gemm_bf16<IDIM, 0><<<gd, 256, 0, stream>>>(interb, wtd, counts, list, pout, HDIM);

    out_mix<<<NTOK * HDIM / 4 / 256, 256, 0, stream>>>(pout, topw, out);
}

// Round 3
// 319.435 us; speedup vs baseline: 5.2857x; 1.2763x over previous
//
#include <hip/hip_runtime.h>
#include <hip/hip_bf16.h>

#define NTOK 4096   // B*T
#define HDIM 1024
#define IDIM 2048
#define NEXP 8
#define RBLK 16     // tokens per routing block

typedef __attribute__((ext_vector_type(8))) short short8;
typedef __attribute__((ext_vector_type(4))) short short4b;
typedef __attribute__((ext_vector_type(4))) float f32x4;
typedef unsigned short ushort_t;

__device__ inline ushort_t f2bf(float f) {
    union { float f; unsigned u; } v; v.f = f;
    unsigned r = v.u + 0x7FFFu + ((v.u >> 16) & 1u);
    return (ushort_t)(r >> 16);
}
__device__ inline float bf2f(ushort_t h) {
    union { unsigned u; float f; } v; v.u = ((unsigned)h) << 16;
    return v.f;
}

#define GPTR(p) ((const __attribute__((address_space(1))) void*)(p))
#define LPTR(p) ((__attribute__((address_space(3))) void*)(p))

// ---------------- routing: 256 blocks, 16 tokens each (1 wave/token x 4 iters) ----------------
__global__ __launch_bounds__(256) void routing_kernel(
    const float* __restrict__ x, const float* __restrict__ qw,
    const float* __restrict__ kp, const float* __restrict__ vp,
    float* __restrict__ rw_out, int* __restrict__ counts,
    int* __restrict__ list, float2* __restrict__ topw,
    ushort_t* __restrict__ xb)
{
    __shared__ float kp_s[NEXP * HDIM];     // 32 KB
    __shared__ float vp_s[NEXP * NEXP];
    __shared__ int lcnt[NEXP];
    __shared__ int base_s[NEXP];
    __shared__ int tinfo[RBLK][4];          // e0,p0,e1,p1

    int tid = threadIdx.x;
    int wid = tid >> 6, lane = tid & 63;

    if (tid < NEXP) lcnt[tid] = 0;
    if (tid < NEXP * NEXP) vp_s[tid] = vp[tid];
    #pragma unroll
    for (int i = 0; i < 8; i++)
        ((float4*)kp_s)[tid + 256 * i] = ((const float4*)kp)[tid + 256 * i];

    float4 qv[4];
    #pragma unroll
    for (int j = 0; j < 4; j++) qv[j] = ((const float4*)qw)[lane + 64 * j];
    __syncthreads();

    for (int it = 0; it < RBLK / 4; it++) {
        int tl = wid * (RBLK / 4) + it;
        int t = blockIdx.x * RBLK + tl;
        const float4* xr4 = (const float4*)(x + (size_t)t * HDIM);
        float4 xv[4];
        #pragma unroll
        for (int j = 0; j < 4; j++) xv[j] = xr4[lane + 64 * j];

        // fused bf16 conversion of x (raw x feeds the gate/up GEMM)
        ushort_t* xrow = xb + (size_t)t * HDIM;
        #pragma unroll
        for (int j = 0; j < 4; j++) {
            short4b o;
            o[0] = f2bf(xv[j].x); o[1] = f2bf(xv[j].y);
            o[2] = f2bf(xv[j].z); o[3] = f2bf(xv[j].w);
            ((short4b*)xrow)[lane + 64 * j] = o;
        }

        float ss = 0.f;
        #pragma unroll
        for (int j = 0; j < 4; j++)
            ss += xv[j].x*xv[j].x + xv[j].y*xv[j].y + xv[j].z*xv[j].z + xv[j].w*xv[j].w;
        #pragma unroll
        for (int off = 32; off; off >>= 1) ss += __shfl_xor(ss, off);
        float rms = rsqrtf(ss * (1.0f / HDIM) + 1e-6f);

        float4 q[4];
        #pragma unroll
        for (int j = 0; j < 4; j++) {
            q[j].x = xv[j].x * rms * qv[j].x; q[j].y = xv[j].y * rms * qv[j].y;
            q[j].z = xv[j].z * rms * qv[j].z; q[j].w = xv[j].w * rms * qv[j].w;
        }

        float d[NEXP];
        #pragma unroll
        for (int p = 0; p < NEXP; p++) {
            float acc = 0.f;
            #pragma unroll
            for (int j = 0; j < 4; j++) {
                float4 kv = ((const float4*)kp_s)[p * 256 + lane + 64 * j];
                acc += q[j].x*kv.x + q[j].y*kv.y + q[j].z*kv.z + q[j].w*kv.w;
            }
            #pragma unroll
            for (int off = 32; off; off >>= 1) acc += __shfl_xor(acc, off);
            d[p] = acc * (1.0f / 32.0f);   // /sqrt(1024)
        }

        // tail: wave-uniform (costs same as lane-0-only)
        float m = d[0];
        #pragma unroll
        for (int p = 1; p < NEXP; p++) m = fmaxf(m, d[p]);
        float a[NEXP]; float s = 0.f;
        #pragma unroll
        for (int p = 0; p < NEXP; p++) { a[p] = expf(d[p] - m); s += a[p]; }
        float inv = 1.0f / s;
        #pragma unroll
        for (int p = 0; p < NEXP; p++) a[p] *= inv;
        float lg[NEXP];
        #pragma unroll
        for (int qi = 0; qi < NEXP; qi++) {
            float acc = 0.f;
            #pragma unroll
            for (int p = 0; p < NEXP; p++) acc += a[p] * vp_s[p * NEXP + qi];
            lg[qi] = acc;
        }
        float m2 = lg[0];
        #pragma unroll
        for (int p = 1; p < NEXP; p++) m2 = fmaxf(m2, lg[p]);
        float r[NEXP]; float s2 = 0.f;
        #pragma unroll
        for (int p = 0; p < NEXP; p++) { r[p] = expf(lg[p] - m2); s2 += r[p]; }
        float inv2 = 1.0f / s2;
        #pragma unroll
        for (int p = 0; p < NEXP; p++) r[p] *= inv2;
        int e0 = -1, e1 = -1; float w0 = -1.f, w1 = -1.f;
        #pragma unroll
        for (int p = 0; p < NEXP; p++) {
            if (r[p] > w0) { w1 = w0; e1 = e0; w0 = r[p]; e0 = p; }
            else if (r[p] > w1) { w1 = r[p]; e1 = p; }
        }
        float invn = 1.0f / (w0 + w1 + 1e-9f);
        float w0n = w0 * invn, w1n = w1 * invn;

        if (lane == 0) {
            #pragma unroll
            for (int p = 0; p < NEXP; p++)
                rw_out[(size_t)t * NEXP + p] = (p == e0) ? w0n : ((p == e1) ? w1n : 0.f);
            topw[t] = make_float2(w0n, w1n);
            int p0 = atomicAdd(&lcnt[e0], 1);
            int p1 = atomicAdd(&lcnt[e1], 1);
            tinfo[tl][0] = e0; tinfo[tl][1] = p0;
            tinfo[tl][2] = e1; tinfo[tl][3] = p1;
        }
    }
    __syncthreads();
    if (tid < NEXP) base_s[tid] = atomicAdd(&counts[tid], lcnt[tid]);
    __syncthreads();
    if (tid < RBLK) {
        int t = blockIdx.x * RBLK + tid;
        int e0 = tinfo[tid][0], p0 = tinfo[tid][1];
        int e1 = tinfo[tid][2], p1 = tinfo[tid][3];
        list[e0 * NTOK + base_s[e0] + p0] = t * 2;
        list[e1 * NTOK + base_s[e1] + p1] = t * 2 + 1;
    }
}

// ------- convert + transpose weights: fp32 [E][K][N] -> bf16 [E][N][K] -------
// grid (N/64, K/64, E), block 256
__global__ __launch_bounds__(256) void conv_t(const float* __restrict__ in, ushort_t* __restrict__ out,
                                              int K, int N) {
    __shared__ ushort_t ts[64][72];
    int e = blockIdx.z;
    const float* ip = in + (size_t)e * K * N + (size_t)(blockIdx.y * 64) * N + blockIdx.x * 64;
    ushort_t* op = out + (size_t)e * K * N + (size_t)(blockIdx.x * 64) * K + blockIdx.y * 64;
    int tid = threadIdx.x;
    int r0 = tid >> 4;            // 0..15
    int c4 = (tid & 15) * 4;
    #pragma unroll
    for (int i = 0; i < 4; i++) {
        int r = r0 + i * 16;
        float4 v = *(const float4*)(ip + (size_t)r * N + c4);
        ts[c4+0][r] = f2bf(v.x); ts[c4+1][r] = f2bf(v.y);
        ts[c4+2][r] = f2bf(v.z); ts[c4+3][r] = f2bf(v.w);
    }
    __syncthreads();
    int n = tid >> 2;             // 0..63
    int kq = (tid & 3) * 16;
    short8 w0 = *(const short8*)&ts[n][kq];
    short8 w1 = *(const short8*)&ts[n][kq + 8];
    ushort_t* dst = op + (size_t)n * K + kq;
    ((short8*)dst)[0] = w0;
    ((short8*)dst)[1] = w1;
}

// ------- grouped bf16 MFMA GEMM: C[ent][col] = sum_k A[tok][k] * Wt[e][col][k] -------
template<int K, int OUTBF>
__global__ __launch_bounds__(256) void gemm_bf16(
    const ushort_t* __restrict__ A, const ushort_t* __restrict__ W,
    const int* __restrict__ counts, const int* __restrict__ list,
    void* __restrict__ outp, int odim)
{
    int e = blockIdx.z;
    int M = counts[e];
    int row0 = blockIdx.y * 128;
    if (row0 >= M) return;
    int col0 = blockIdx.x * 128;

    __shared__ ushort_t Abuf[128 * 32];
    __shared__ ushort_t Bbuf[128 * 32];
    __shared__ int rowsS[128];

    int tid = threadIdx.x;
    if (tid < 128) {
        int r = row0 + tid;
        rowsS[tid] = (r < M) ? list[e * NTOK + r] : -1;
    }
    __syncthreads();

    int s0 = tid, s1 = tid + 256;
    int er0 = rowsS[s0 >> 2], er1 = rowsS[s1 >> 2];
    const ushort_t* gA0 = A + (size_t)(er0 >= 0 ? (er0 >> 1) : 0) * K + (s0 & 3) * 8;
    const ushort_t* gA1 = A + (size_t)(er1 >= 0 ? (er1 >> 1) : 0) * K + (s1 & 3) * 8;
    const ushort_t* We = W + (size_t)e * odim * K;
    const ushort_t* gB0 = We + (size_t)(col0 + (s0 >> 2)) * K + (s0 & 3) * 8;
    const ushort_t* gB1 = We + (size_t)(col0 + (s1 >> 2)) * K + (s1 & 3) * 8;

    int wid = tid >> 6, lane = tid & 63;
    int wr = wid >> 1, wc = wid & 1;
    int la = lane & 15, lb = lane >> 4;

    ushort_t* ldsA = Abuf + wid * 64 * 8;
    ushort_t* ldsB = Bbuf + wid * 64 * 8;

    int aoff[4], boff[4];
    #pragma unroll
    for (int m = 0; m < 4; m++) aoff[m] = (wr * 64 + m * 16 + la) * 32 + lb * 8;
    #pragma unroll
    for (int n = 0; n < 4; n++) boff[n] = (wc * 64 + n * 16 + la) * 32 + lb * 8;

    f32x4 acc[4][4];
    #pragma unroll
    for (int m = 0; m < 4; m++)
        #pragma unroll
        for (int n = 0; n < 4; n++) acc[m][n] = (f32x4){0.f, 0.f, 0.f, 0.f};

    for (int k0 = 0; k0 < K; k0 += 32) {
        __builtin_amdgcn_global_load_lds(GPTR(gA0 + k0), LPTR(ldsA),            16, 0, 0);
        __builtin_amdgcn_global_load_lds(GPTR(gA1 + k0), LPTR(ldsA + 256 * 8),  16, 0, 0);
        __builtin_amdgcn_global_load_lds(GPTR(gB0 + k0), LPTR(ldsB),            16, 0, 0);
        __builtin_amdgcn_global_load_lds(GPTR(gB1 + k0), LPTR(ldsB + 256 * 8),  16, 0, 0);
        __syncthreads();
        short8 af[4], bfr[4];
        #pragma unroll
        for (int m = 0; m < 4; m++) af[m] = *(const short8*)&Abuf[aoff[m]];
        #pragma unroll
        for (int n = 0; n < 4; n++) bfr[n] = *(const short8*)&Bbuf[boff[n]];
        #pragma unroll
        for (int m = 0; m < 4; m++)
            #pragma unroll
            for (int n = 0; n < 4; n++)
                acc[m][n] = __builtin_amdgcn_mfma_f32_16x16x32_bf16(af[m], bfr[n], acc[m][n], 0, 0, 0);
        __syncthreads();
    }

    #pragma unroll
    for (int m = 0; m < 4; m++) {
        #pragma unroll
        for (int j = 0; j < 4; j++) {
            int rl = wr * 64 + m * 16 + lb * 4 + j;
            int ent = rowsS[rl];
            if (ent >= 0) {
                size_t base = (size_t)ent * odim + col0 + wc * 64 + la;
                #pragma unroll
                for (int n = 0; n < 4; n++) {
                    if (OUTBF) ((ushort_t*)outp)[base + n * 16] = f2bf(acc[m][n][j]);
                    else       ((float*)outp)[base + n * 16] = acc[m][n][j];
                }
            }
        }
    }
}

// ------- elementwise: mix pairs (bf16 in), silu, write bf16 inter -------
__global__ __launch_bounds__(256) void silu_mix(
    const ushort_t* __restrict__ bg, const ushort_t* __restrict__ bu,
    const float2* __restrict__ topw, ushort_t* __restrict__ inter)
{
    int idx = blockIdx.x * 256 + threadIdx.x;          // over NTOK*IDIM/8
    int t = idx >> 8;                                  // IDIM/8 = 256
    int i8 = (idx & 255) * 8;
    float2 w = topw[t];
    short8 g0 = *(const short8*)(bg + (size_t)(2*t)   * IDIM + i8);
    short8 g1 = *(const short8*)(bg + (size_t)(2*t+1) * IDIM + i8);
    short8 u0 = *(const short8*)(bu + (size_t)(2*t)   * IDIM + i8);
    short8 u1 = *(const short8*)(bu + (size_t)(2*t+1) * IDIM + i8);
    short8 r;
    #pragma unroll
    for (int j = 0; j < 8; j++) {
        float g = w.x * bf2f((ushort_t)g0[j]) + w.y * bf2f((ushort_t)g1[j]);
        float u = w.x * bf2f((ushort_t)u0[j]) + w.y * bf2f((ushort_t)u1[j]);
        float s = g / (1.f + expf(-g)) * u;
        r[j] = f2bf(s);
    }
    *(short8*)(inter + (size_t)t * IDIM + i8) = r;
}

// ------- final: weighted pair reduce into output -------
__global__ __launch_bounds__(256) void out_mix(
    const float* __restrict__ pout, const float2* __restrict__ topw,
    float* __restrict__ out)
{
    int idx = blockIdx.x * 256 + threadIdx.x;          // over NTOK*HDIM/4
    int t = idx >> 8;                                  // HDIM/4 = 256
    int h4 = (idx & 255) * 4;
    float2 w = topw[t];
    float4 a = *(const float4*)(pout + (size_t)(2*t)   * HDIM + h4);
    float4 b = *(const float4*)(pout + (size_t)(2*t+1) * HDIM + h4);
    float4 r;
    r.x = w.x*a.x + w.y*b.x;
    r.y = w.x*a.y + w.y*b.y;
    r.z = w.x*a.z + w.y*b.z;
    r.w = w.x*a.w + w.y*b.w;
    *(float4*)(out + (size_t)t * HDIM + h4) = r;
}

extern "C" void kernel_launch(void* const* d_in, const int* in_sizes, int n_in,
                              void* d_out, int out_size, void* d_ws, size_t ws_size,
                              hipStream_t stream) {
    const float* x    = (const float*)d_in[0];
    const float* qw   = (const float*)d_in[1];
    const float* kp   = (const float*)d_in[2];
    const float* vp   = (const float*)d_in[3];
    const float* gate = (const float*)d_in[4];
    const float* up   = (const float*)d_in[5];
    const float* down = (const float*)d_in[6];
    float* out = (float*)d_out;
    float* rw_out = out + (size_t)NTOK * HDIM;

    char* ws = (char*)d_ws;
    int*      counts = (int*)ws;                          // 32 B
    float2*   topw   = (float2*)(ws + 1024);              // 32 KB
    int*      list   = (int*)(ws + 64 * 1024);            // 128 KB
    ushort_t* xb     = (ushort_t*)(ws + 256 * 1024);      // 8 MB
    ushort_t* wtg    = xb + (size_t)NTOK * HDIM;          // 32 MB  (bf16 [E][I][H])
    ushort_t* wtu    = wtg + (size_t)NEXP * HDIM * IDIM;  // 32 MB
    ushort_t* wtd    = wtu + (size_t)NEXP * HDIM * IDIM;  // 32 MB  (bf16 [E][H][I])
    ushort_t* bg     = wtd + (size_t)NEXP * HDIM * IDIM;  // 33.5 MB (bf16 [8192][I])
    ushort_t* bu     = bg  + (size_t)2 * NTOK * IDIM;     // 33.5 MB
    ushort_t* interb = bu  + (size_t)2 * NTOK * IDIM;     // 16.8 MB (bf16 [NTOK][I])
    float*    pout   = (float*)bg;                        // alias (bg dead after silu_mix)

    hipMemsetAsync(counts, 0, NEXP * sizeof(int), stream);

    routing_kernel<<<NTOK / RBLK, 256, 0, stream>>>(x, qw, kp, vp, rw_out, counts, list, topw, xb);

    conv_t<<<dim3(IDIM / 64, HDIM / 64, NEXP), 256, 0, stream>>>(gate, wtg, HDIM, IDIM);
    conv_t<<<dim3(IDIM / 64, HDIM / 64, NEXP), 256, 0, stream>>>(up,   wtu, HDIM, IDIM);
    conv_t<<<dim3(HDIM / 64, IDIM / 64, NEXP), 256, 0, stream>>>(down, wtd, IDIM, HDIM);

    dim3 ggu(IDIM / 128, NTOK / 128, NEXP);   // (16, 32, 8)
    gemm_bf16<HDIM, 1><<<ggu, 256, 0, stream>>>(xb, wtg, counts, list, bg, IDIM);
    gemm_bf16<HDIM, 1><<<ggu, 256, 0, stream>>>(xb, wtu, counts, list, bu, IDIM);

    silu_mix<<<NTOK * IDIM / 8 / 256, 256, 0, stream>>>(bg, bu, topw, interb);

    dim3 gd(HDIM / 128, NTOK / 128, NEXP);    // (8, 32, 8)
    gemm_bf16<IDIM, 0><<<gd, 256, 0, stream>>>(interb, wtd, counts, list, pout, HDIM);

    out_mix<<<NTOK * HDIM / 4 / 256, 256, 0, stream>>>(pout, topw, out);
}

// Round 4
// 255.945 us; speedup vs baseline: 6.5969x; 1.2481x over previous
//
#include <hip/hip_runtime.h>
#include <hip/hip_bf16.h>

#define NTOK 4096   // B*T
#define HDIM 1024
#define IDIM 2048
#define NEXP 8
#define RBLK 16     // tokens per routing block

typedef __attribute__((ext_vector_type(8))) short short8;
typedef __attribute__((ext_vector_type(4))) short short4b;
typedef __attribute__((ext_vector_type(4))) float f32x4;
typedef unsigned short ushort_t;

__device__ inline ushort_t f2bf(float f) {
    union { float f; unsigned u; } v; v.f = f;
    unsigned r = v.u + 0x7FFFu + ((v.u >> 16) & 1u);
    return (ushort_t)(r >> 16);
}
__device__ inline float bf2f(ushort_t h) {
    union { unsigned u; float f; } v; v.u = ((unsigned)h) << 16;
    return v.f;
}

#define GPTR(p) ((const __attribute__((address_space(1))) void*)(p))
#define LPTR(p) ((__attribute__((address_space(3))) void*)(p))

// ---------------- routing: 256 blocks, 16 tokens each (1 wave/token x 4 iters) ----------------
__global__ __launch_bounds__(256) void routing_kernel(
    const float* __restrict__ x, const float* __restrict__ qw,
    const float* __restrict__ kp, const float* __restrict__ vp,
    float* __restrict__ rw_out, int* __restrict__ counts,
    int* __restrict__ list, float2* __restrict__ topw,
    ushort_t* __restrict__ xb)
{
    __shared__ float kp_s[NEXP * HDIM];     // 32 KB
    __shared__ float vp_s[NEXP * NEXP];
    __shared__ int lcnt[NEXP];
    __shared__ int base_s[NEXP];
    __shared__ int tinfo[RBLK][4];          // e0,p0,e1,p1

    int tid = threadIdx.x;
    int wid = tid >> 6, lane = tid & 63;

    if (tid < NEXP) lcnt[tid] = 0;
    if (tid < NEXP * NEXP) vp_s[tid] = vp[tid];
    #pragma unroll
    for (int i = 0; i < 8; i++)
        ((float4*)kp_s)[tid + 256 * i] = ((const float4*)kp)[tid + 256 * i];

    float4 qv[4];
    #pragma unroll
    for (int j = 0; j < 4; j++) qv[j] = ((const float4*)qw)[lane + 64 * j];
    __syncthreads();

    for (int it = 0; it < RBLK / 4; it++) {
        int tl = wid * (RBLK / 4) + it;
        int t = blockIdx.x * RBLK + tl;
        const float4* xr4 = (const float4*)(x + (size_t)t * HDIM);
        float4 xv[4];
        #pragma unroll
        for (int j = 0; j < 4; j++) xv[j] = xr4[lane + 64 * j];

        // fused bf16 conversion of x
        ushort_t* xrow = xb + (size_t)t * HDIM;
        #pragma unroll
        for (int j = 0; j < 4; j++) {
            short4b o;
            o[0] = f2bf(xv[j].x); o[1] = f2bf(xv[j].y);
            o[2] = f2bf(xv[j].z); o[3] = f2bf(xv[j].w);
            ((short4b*)xrow)[lane + 64 * j] = o;
        }

        float ss = 0.f;
        #pragma unroll
        for (int j = 0; j < 4; j++)
            ss += xv[j].x*xv[j].x + xv[j].y*xv[j].y + xv[j].z*xv[j].z + xv[j].w*xv[j].w;
        #pragma unroll
        for (int off = 32; off; off >>= 1) ss += __shfl_xor(ss, off);
        float rms = rsqrtf(ss * (1.0f / HDIM) + 1e-6f);

        float4 q[4];
        #pragma unroll
        for (int j = 0; j < 4; j++) {
            q[j].x = xv[j].x * rms * qv[j].x; q[j].y = xv[j].y * rms * qv[j].y;
            q[j].z = xv[j].z * rms * qv[j].z; q[j].w = xv[j].w * rms * qv[j].w;
        }

        float d[NEXP];
        #pragma unroll
        for (int p = 0; p < NEXP; p++) {
            float acc = 0.f;
            #pragma unroll
            for (int j = 0; j < 4; j++) {
                float4 kv = ((const float4*)kp_s)[p * 256 + lane + 64 * j];
                acc += q[j].x*kv.x + q[j].y*kv.y + q[j].z*kv.z + q[j].w*kv.w;
            }
            #pragma unroll
            for (int off = 32; off; off >>= 1) acc += __shfl_xor(acc, off);
            d[p] = acc * (1.0f / 32.0f);   // /sqrt(1024)
        }

        float m = d[0];
        #pragma unroll
        for (int p = 1; p < NEXP; p++) m = fmaxf(m, d[p]);
        float a[NEXP]; float s = 0.f;
        #pragma unroll
        for (int p = 0; p < NEXP; p++) { a[p] = expf(d[p] - m); s += a[p]; }
        float inv = 1.0f / s;
        #pragma unroll
        for (int p = 0; p < NEXP; p++) a[p] *= inv;
        float lg[NEXP];
        #pragma unroll
        for (int qi = 0; qi < NEXP; qi++) {
            float acc = 0.f;
            #pragma unroll
            for (int p = 0; p < NEXP; p++) acc += a[p] * vp_s[p * NEXP + qi];
            lg[qi] = acc;
        }
        float m2 = lg[0];
        #pragma unroll
        for (int p = 1; p < NEXP; p++) m2 = fmaxf(m2, lg[p]);
        float r[NEXP]; float s2 = 0.f;
        #pragma unroll
        for (int p = 0; p < NEXP; p++) { r[p] = expf(lg[p] - m2); s2 += r[p]; }
        float inv2 = 1.0f / s2;
        #pragma unroll
        for (int p = 0; p < NEXP; p++) r[p] *= inv2;
        int e0 = -1, e1 = -1; float w0 = -1.f, w1 = -1.f;
        #pragma unroll
        for (int p = 0; p < NEXP; p++) {
            if (r[p] > w0) { w1 = w0; e1 = e0; w0 = r[p]; e0 = p; }
            else if (r[p] > w1) { w1 = r[p]; e1 = p; }
        }
        float invn = 1.0f / (w0 + w1 + 1e-9f);
        float w0n = w0 * invn, w1n = w1 * invn;

        if (lane == 0) {
            #pragma unroll
            for (int p = 0; p < NEXP; p++)
                rw_out[(size_t)t * NEXP + p] = (p == e0) ? w0n : ((p == e1) ? w1n : 0.f);
            topw[t] = make_float2(w0n, w1n);
            int p0 = atomicAdd(&lcnt[e0], 1);
            int p1 = atomicAdd(&lcnt[e1], 1);
            tinfo[tl][0] = e0; tinfo[tl][1] = p0;
            tinfo[tl][2] = e1; tinfo[tl][3] = p1;
        }
    }
    __syncthreads();
    if (tid < NEXP) base_s[tid] = atomicAdd(&counts[tid], lcnt[tid]);
    __syncthreads();
    if (tid < RBLK) {
        int t = blockIdx.x * RBLK + tid;
        int e0 = tinfo[tid][0], p0 = tinfo[tid][1];
        int e1 = tinfo[tid][2], p1 = tinfo[tid][3];
        list[e0 * NTOK + base_s[e0] + p0] = t * 2;
        list[e1 * NTOK + base_s[e1] + p1] = t * 2 + 1;
    }
}

// ------- weights: fp32 [E][K][N] -> bf16 tiled [E][N/128][K/64][128][64], bank-swizzle baked -------
// grid (N/64, K/64, E), block 256. Tile[r][c] = bf16(in[k = kb*64 + (c ^ ((r&7)<<3))][n = nb*128 + r])
__global__ __launch_bounds__(256) void conv_t(const float* __restrict__ in, ushort_t* __restrict__ out,
                                              int K, int N) {
    __shared__ ushort_t ts[64][72];
    int e = blockIdx.z;
    int xb = blockIdx.x, yb = blockIdx.y;
    const float* ip = in + (size_t)e * K * N + (size_t)(yb * 64) * N + xb * 64;
    int NB = N / 128, KB = K / 64;
    int nb = xb >> 1, rhalf = (xb & 1) * 64;
    ushort_t* op = out + ((size_t)((size_t)e * NB + nb) * KB + yb) * (128 * 64);

    int tid = threadIdx.x;
    int r0 = tid >> 4;            // k-row 0..15
    int c4 = (tid & 15) * 4;      // n-col
    #pragma unroll
    for (int i = 0; i < 4; i++) {
        int r = r0 + i * 16;
        float4 v = *(const float4*)(ip + (size_t)r * N + c4);
        ts[c4+0][r] = f2bf(v.x); ts[c4+1][r] = f2bf(v.y);
        ts[c4+2][r] = f2bf(v.z); ts[c4+3][r] = f2bf(v.w);
    }
    __syncthreads();
    int n = tid >> 2;             // 0..63 local n
    int kq = (tid & 3) * 16;
    int sw = (n & 7) << 3;        // ushort xor (row&7 within tile; rhalf is mult of 64)
    short8 w0 = *(const short8*)&ts[n][kq];
    short8 w1 = *(const short8*)&ts[n][kq + 8];
    ushort_t* dst = op + (size_t)(rhalf + n) * 64;
    *(short8*)(dst + (kq ^ sw))       = w0;
    *(short8*)(dst + ((kq + 8) ^ sw)) = w1;
}

// ------- grouped bf16 MFMA GEMM, 128x128 tile, BK=64, swizzled LDS, coalesced staging -------
// W layout: tiled [E][odim/128][K/64][128][64] (swizzle baked). A: bf16 rows, gathered.
template<int K, int FUSED, int OUTBF>
__global__ __launch_bounds__(256) void gemm_bf16(
    const ushort_t* __restrict__ A,
    const ushort_t* __restrict__ W0, const ushort_t* __restrict__ W1,
    const int* __restrict__ counts, const int* __restrict__ list,
    void* __restrict__ out0, void* __restrict__ out1, int odim)
{
    constexpr int KB = K / 64;
    int e = blockIdx.z;
    int M = counts[e];
    int row0 = blockIdx.y * 128;
    if (row0 >= M) return;
    int nbTiles = odim / 128;
    int colb = blockIdx.x;
    const ushort_t* W = (FUSED && colb >= nbTiles) ? W1 : W0;
    void* outp        = (FUSED && colb >= nbTiles) ? out1 : out0;
    int nb = (FUSED && colb >= nbTiles) ? colb - nbTiles : colb;
    int col0 = nb * 128;

    __shared__ ushort_t Abuf[128 * 64];   // [row][64], swizzled content
    __shared__ ushort_t Bbuf[128 * 64];
    __shared__ int rowsS[128];

    int tid = threadIdx.x;
    if (tid < 128) {
        int r = row0 + tid;
        rowsS[tid] = (r < M) ? list[e * NTOK + r] : -1;
    }
    __syncthreads();

    int wid = tid >> 6, lane = tid & 63;
    int wr = wid >> 1, wc = wid & 1;
    int la = lane & 15, lb = lane >> 4;

    // ---- A staging: seg = wid*4+i covers rows seg*8..+7; lane -> row seg*8+(lane>>3),
    // 16B chunk (lane&7), source k pre-swizzled so LDS stays linear (rule 21 / m173).
    int swu = ((((lane & 7) * 16) ^ ((lane >> 3) << 4)) >> 1);   // element offset in row
    const ushort_t* aP[4];
    #pragma unroll
    for (int i = 0; i < 4; i++) {
        int r = (wid * 4 + i) * 8 + (lane >> 3);
        int ent = rowsS[r];
        int tok = (ent >= 0) ? (ent >> 1) : 0;
        aP[i] = A + (size_t)tok * K + swu;
    }
    // ---- B staging: tile is linear+pre-swizzled in memory -> pure linear copy
    const ushort_t* Wt = W + (size_t)((size_t)e * nbTiles + nb) * KB * (128 * 64);

    // ---- fragment read offsets (ushort idx), reader applies the XOR
    int swr = (la & 7) << 3;
    int aoff[4][2], boff[4][2];
    #pragma unroll
    for (int m = 0; m < 4; m++)
        #pragma unroll
        for (int ks = 0; ks < 2; ks++)
            aoff[m][ks] = (wr * 64 + m * 16 + la) * 64 + ((ks * 32 + lb * 8) ^ swr);
    #pragma unroll
    for (int n = 0; n < 4; n++)
        #pragma unroll
        for (int ks = 0; ks < 2; ks++)
            boff[n][ks] = (wc * 64 + n * 16 + la) * 64 + ((ks * 32 + lb * 8) ^ swr);

    f32x4 acc[4][4];
    #pragma unroll
    for (int m = 0; m < 4; m++)
        #pragma unroll
        for (int n = 0; n < 4; n++) acc[m][n] = (f32x4){0.f, 0.f, 0.f, 0.f};

    for (int kt = 0; kt < KB; kt++) {
        #pragma unroll
        for (int i = 0; i < 4; i++) {
            int seg = wid * 4 + i;
            __builtin_amdgcn_global_load_lds(GPTR(aP[i] + kt * 64),
                                             LPTR(Abuf + seg * 512), 16, 0, 0);
            __builtin_amdgcn_global_load_lds(GPTR(Wt + (size_t)kt * 8192 + seg * 512 + lane * 8),
                                             LPTR(Bbuf + seg * 512), 16, 0, 0);
        }
        __syncthreads();
        #pragma unroll
        for (int ks = 0; ks < 2; ks++) {
            short8 af[4], bf[4];
            #pragma unroll
            for (int m = 0; m < 4; m++) af[m] = *(const short8*)&Abuf[aoff[m][ks]];
            #pragma unroll
            for (int n = 0; n < 4; n++) bf[n] = *(const short8*)&Bbuf[boff[n][ks]];
            #pragma unroll
            for (int m = 0; m < 4; m++)
                #pragma unroll
                for (int n = 0; n < 4; n++)
                    acc[m][n] = __builtin_amdgcn_mfma_f32_16x16x32_bf16(af[m], bf[n], acc[m][n], 0, 0, 0);
        }
        __syncthreads();
    }

    #pragma unroll
    for (int m = 0; m < 4; m++) {
        #pragma unroll
        for (int j = 0; j < 4; j++) {
            int rl = wr * 64 + m * 16 + lb * 4 + j;
            int ent = rowsS[rl];
            if (ent >= 0) {
                size_t base = (size_t)ent * odim + col0 + wc * 64 + la;
                #pragma unroll
                for (int n = 0; n < 4; n++) {
                    if (OUTBF) ((ushort_t*)outp)[base + n * 16] = f2bf(acc[m][n][j]);
                    else       ((float*)outp)[base + n * 16] = acc[m][n][j];
                }
            }
        }
    }
}

// ------- elementwise: mix pairs (bf16 in), silu, write bf16 inter -------
__global__ __launch_bounds__(256) void silu_mix(
    const ushort_t* __restrict__ bg, const ushort_t* __restrict__ bu,
    const float2* __restrict__ topw, ushort_t* __restrict__ inter)
{
    int idx = blockIdx.x * 256 + threadIdx.x;          // over NTOK*IDIM/8
    int t = idx >> 8;                                  // IDIM/8 = 256
    int i8 = (idx & 255) * 8;
    float2 w = topw[t];
    short8 g0 = *(const short8*)(bg + (size_t)(2*t)   * IDIM + i8);
    short8 g1 = *(const short8*)(bg + (size_t)(2*t+1) * IDIM + i8);
    short8 u0 = *(const short8*)(bu + (size_t)(2*t)   * IDIM + i8);
    short8 u1 = *(const short8*)(bu + (size_t)(2*t+1) * IDIM + i8);
    short8 r;
    #pragma unroll
    for (int j = 0; j < 8; j++) {
        float g = w.x * bf2f((ushort_t)g0[j]) + w.y * bf2f((ushort_t)g1[j]);
        float u = w.x * bf2f((ushort_t)u0[j]) + w.y * bf2f((ushort_t)u1[j]);
        float s = g / (1.f + expf(-g)) * u;
        r[j] = f2bf(s);
    }
    *(short8*)(inter + (size_t)t * IDIM + i8) = r;
}

// ------- final: weighted pair reduce into output -------
__global__ __launch_bounds__(256) void out_mix(
    const float* __restrict__ pout, const float2* __restrict__ topw,
    float* __restrict__ out)
{
    int idx = blockIdx.x * 256 + threadIdx.x;          // over NTOK*HDIM/4
    int t = idx >> 8;                                  // HDIM/4 = 256
    int h4 = (idx & 255) * 4;
    float2 w = topw[t];
    float4 a = *(const float4*)(pout + (size_t)(2*t)   * HDIM + h4);
    float4 b = *(const float4*)(pout + (size_t)(2*t+1) * HDIM + h4);
    float4 r;
    r.x = w.x*a.x + w.y*b.x;
    r.y = w.x*a.y + w.y*b.y;
    r.z = w.x*a.z + w.y*b.z;
    r.w = w.x*a.w + w.y*b.w;
    *(float4*)(out + (size_t)t * HDIM + h4) = r;
}

extern "C" void kernel_launch(void* const* d_in, const int* in_sizes, int n_in,
                              void* d_out, int out_size, void* d_ws, size_t ws_size,
                              hipStream_t stream) {
    const float* x    = (const float*)d_in[0];
    const float* qw   = (const float*)d_in[1];
    const float* kp   = (const float*)d_in[2];
    const float* vp   = (const float*)d_in[3];
    const float* gate = (const float*)d_in[4];
    const float* up   = (const float*)d_in[5];
    const float* down = (const float*)d_in[6];
    float* out = (float*)d_out;
    float* rw_out = out + (size_t)NTOK * HDIM;

    char* ws = (char*)d_ws;
    int*      counts = (int*)ws;                          // 32 B
    float2*   topw   = (float2*)(ws + 1024);              // 32 KB
    int*      list   = (int*)(ws + 64 * 1024);            // 128 KB
    ushort_t* xb     = (ushort_t*)(ws + 256 * 1024);      // 8 MB
    ushort_t* wtg    = xb + (size_t)NTOK * HDIM;          // 32 MB (tiled bf16)
    ushort_t* wtu    = wtg + (size_t)NEXP * HDIM * IDIM;  // 32 MB
    ushort_t* wtd    = wtu + (size_t)NEXP * HDIM * IDIM;  // 32 MB
    ushort_t* bg     = wtd + (size_t)NEXP * HDIM * IDIM;  // 33.5 MB (bf16 [8192][I])
    ushort_t* bu     = bg  + (size_t)2 * NTOK * IDIM;     // 33.5 MB
    ushort_t* interb = bu  + (size_t)2 * NTOK * IDIM;     // 16.8 MB (bf16 [NTOK][I])
    float*    pout   = (float*)bg;                        // alias (bg dead after silu_mix)

    hipMemsetAsync(counts, 0, NEXP * sizeof(int), stream);

    routing_kernel<<<NTOK / RBLK, 256, 0, stream>>>(x, qw, kp, vp, rw_out, counts, list, topw, xb);

    conv_t<<<dim3(IDIM / 64, HDIM / 64, NEXP), 256, 0, stream>>>(gate, wtg, HDIM, IDIM);
    conv_t<<<dim3(IDIM / 64, HDIM / 64, NEXP), 256, 0, stream>>>(up,   wtu, HDIM, IDIM);
    conv_t<<<dim3(HDIM / 64, IDIM / 64, NEXP), 256, 0, stream>>>(down, wtd, IDIM, HDIM);

    // fused gate+up: cols 0..2047 gate, 2048..4095 up
    dim3 ggu(2 * IDIM / 128, NTOK / 128, NEXP);   // (32, 32, 8)
    gemm_bf16<HDIM, 1, 1><<<ggu, 256, 0, stream>>>(xb, wtg, wtu, counts, list, bg, bu, IDIM);

    silu_mix<<<NTOK * IDIM / 8 / 256, 256, 0, stream>>>(bg, bu, topw, interb);

    dim3 gd(HDIM / 128, NTOK / 128, NEXP);        // (8, 32, 8)
    gemm_bf16<IDIM, 0, 0><<<gd, 256, 0, stream>>>(interb, wtd, (const ushort_t*)nullptr,
                                                  counts, list, pout, nullptr, HDIM);

    out_mix<<<NTOK * HDIM / 4 / 256, 256, 0, stream>>>(pout, topw, out);
}